// Round 5
// baseline (1693.459 us; speedup 1.0000x reference)
//
#include <hip/hip_runtime.h>

typedef unsigned int uint;

constexpr int D_IN   = 768;
constexpr int D_SAE  = 16384;   // 2^14
constexpr int BATCH  = 4096;
constexpr int TOTAL_K = 64 * 4096;              // 262144
constexpr size_t NPRE = (size_t)BATCH * D_SAE;  // 67,108,864

// ---------------- workspace layout (bytes) ----------------
// ctrl[1]=bA ctrl[2]=C_A ctrl[3]=bB ctrl[4]=C_B ctrl[5]=nCand ctrl[6]=tau ctrl[7]=nt
constexpr size_t CTRL_OFF    = 0;                         // 16 uints
constexpr size_t HISTA_OFF   = 64;                        // 4096 uints
constexpr size_t ROWCNT_OFF  = HISTA_OFF + 4096 * 4;      // BATCH uints
constexpr size_t ZERO_BYTES  = ROWCNT_OFF + BATCH * 4;    // memset region end
constexpr size_t ROWOFF_OFF  = ZERO_BYTES;                // BATCH+1 uints (pad)
constexpr size_t CURSOR_OFF  = ROWOFF_OFF + (BATCH + 64) * 4;
constexpr size_t TIEKEEP_OFF = CURSOR_OFF + BATCH * 4;    // 2048 uints
constexpr int    CAND_CAP    = 655360;                    // ~2x expected ~312K
constexpr size_t CAND_OFF    = TIEKEEP_OFF + 2048 * 4;    // uint2 * CAND_CAP (5 MB)
constexpr size_t GROUPED_OFF = CAND_OFF + (size_t)CAND_CAP * 8;  // uint2*(TOTAL_K+2048)

// ---------------- encoder GEMM: pre = relu((x - b_dec) @ W_enc + b_enc) ----------------
// Epilogue also builds the 4096-bin top-12-bit histogram (LDS reused).
// NOTE: accumulation order (k0 ascending by 32, k ascending, fmaf chain) must stay
// bitwise-identical across rounds — the global top-k boundary depends on it.
__global__ __launch_bounds__(256, 4) void enc_gemm(
    const float* __restrict__ x, const float* __restrict__ W,
    const float* __restrict__ benc, const float* __restrict__ bdec,
    float* __restrict__ pre, uint* __restrict__ histA)
{
  __shared__ float smem[8448];      // xs[32][132] | wsh[32][132]; reused as hist[4096]
  float* xs  = smem;                // xs: element (k,row) at k*132+row
  float* wsh = smem + 4224;         // wsh: element (k,col) at k*132+col
  const int tid = threadIdx.x;
  const int ty = tid >> 4, tx = tid & 15;
  const int m0 = blockIdx.y * 128;
  const int n0 = blockIdx.x * 128;

  float acc[8][8];
#pragma unroll
  for (int i = 0; i < 8; ++i)
#pragma unroll
    for (int j = 0; j < 8; ++j) acc[i][j] = 0.f;

  for (int k0 = 0; k0 < D_IN; k0 += 32) {
#pragma unroll
    for (int r = 0; r < 4; ++r) {
      int chunk = tid + 256 * r;
      int row = chunk >> 3, c4 = (chunk & 7) * 4;
      float4 v  = *(const float4*)(x + (size_t)(m0 + row) * D_IN + k0 + c4);
      float4 bd = *(const float4*)(bdec + k0 + c4);
      xs[(c4 + 0) * 132 + row] = v.x - bd.x;
      xs[(c4 + 1) * 132 + row] = v.y - bd.y;
      xs[(c4 + 2) * 132 + row] = v.z - bd.z;
      xs[(c4 + 3) * 132 + row] = v.w - bd.w;
    }
#pragma unroll
    for (int r = 0; r < 4; ++r) {
      int chunk = tid + 256 * r;
      int k = chunk >> 5, c4 = (chunk & 31) * 4;
      float4 v = *(const float4*)(W + (size_t)(k0 + k) * D_SAE + n0 + c4);
      *(float4*)&wsh[k * 132 + c4] = v;
    }
    __syncthreads();
#pragma unroll 8
    for (int k = 0; k < 32; ++k) {
      float a[8], b[8];
      *(float4*)&a[0] = *(const float4*)&xs[k * 132 + ty * 4];
      *(float4*)&a[4] = *(const float4*)&xs[k * 132 + 64 + ty * 4];
      *(float4*)&b[0] = *(const float4*)&wsh[k * 132 + tx * 4];
      *(float4*)&b[4] = *(const float4*)&wsh[k * 132 + 64 + tx * 4];
#pragma unroll
      for (int i = 0; i < 8; ++i)
#pragma unroll
        for (int j = 0; j < 8; ++j)
          acc[i][j] = fmaf(a[i], b[j], acc[i][j]);
    }
    __syncthreads();
  }

  // epilogue: + b_enc, relu, store, LDS histogram of top-12 bits
  uint* h = (uint*)smem;
  for (int i = tid; i < 4096; i += 256) h[i] = 0;
  __syncthreads();
#pragma unroll
  for (int i = 0; i < 8; ++i) {
    int row = m0 + ((i < 4) ? (ty * 4 + i) : (64 + ty * 4 + i - 4));
    float* outr = pre + (size_t)row * D_SAE + n0;
#pragma unroll
    for (int jj = 0; jj < 2; ++jj) {
      int cb = (jj == 0) ? (tx * 4) : (64 + tx * 4);
      float4 be = *(const float4*)(benc + n0 + cb);
      float4 o;
      o.x = fmaxf(acc[i][jj * 4 + 0] + be.x, 0.f);
      o.y = fmaxf(acc[i][jj * 4 + 1] + be.y, 0.f);
      o.z = fmaxf(acc[i][jj * 4 + 2] + be.z, 0.f);
      o.w = fmaxf(acc[i][jj * 4 + 3] + be.w, 0.f);
      *(float4*)(outr + cb) = o;
      uint bx = __float_as_uint(o.x), by = __float_as_uint(o.y);
      uint bz = __float_as_uint(o.z), bw = __float_as_uint(o.w);
      if (bx) atomicAdd(&h[bx >> 20], 1u);
      if (by) atomicAdd(&h[by >> 20], 1u);
      if (bz) atomicAdd(&h[bz >> 20], 1u);
      if (bw) atomicAdd(&h[bw >> 20], 1u);
    }
  }
  __syncthreads();
  for (int i = tid; i < 4096; i += 256) {
    uint c = h[i];
    if (c) atomicAdd(&histA[i], c);
  }
}

// ---------------- stage-0 crossing-bin search ----------------
__global__ __launch_bounds__(256) void select_bin(const uint* __restrict__ hist, uint* ctrl)
{
  __shared__ uint ssum[256];
  int t = threadIdx.x;
  int hi = 4096 - 16 * t;
  uint sum = 0;
  for (int b = hi - 16; b < hi; ++b) sum += hist[b];
  ssum[t] = sum;
  __syncthreads();
  if (t == 0) {
    uint C = 0;
    int tc = 255;
    for (int i = 0; i < 256; ++i) {
      if (C + ssum[i] >= TOTAL_K) { tc = i; break; }
      C += ssum[i];
    }
    int top = 4096 - 16 * tc - 1;
    uint bin = (uint)(top - 15);
    for (int b = top; b >= top - 15; --b) {
      uint c = hist[b];
      if (C + c >= TOTAL_K) { bin = (uint)b; break; }
      C += c;
    }
    ctrl[1] = bin;   // bA
    ctrl[2] = C;     // C_A = count strictly above bin bA
  }
}

// ---------------- collect ALL elements with top12 >= bA (block-aggregated) ----------------
__global__ __launch_bounds__(256) void collect_ge(const uint* __restrict__ pre, uint* __restrict__ ctrl,
                                                  uint2* __restrict__ cand)
{
  __shared__ uint2 ents[4096];
  __shared__ uint scnt, sbase;
  if (threadIdx.x == 0) scnt = 0;
  __syncthreads();
  uint bA = ctrl[1];
  size_t n4 = NPRE / 4;
  size_t stride = (size_t)gridDim.x * 256;
  for (size_t i = (size_t)blockIdx.x * 256 + threadIdx.x; i < n4; i += stride) {
    uint4 v = ((const uint4*)pre)[i];
    uint base = (uint)(i * 4);
#pragma unroll
    for (int c = 0; c < 4; ++c) {
      uint bits = (c == 0) ? v.x : (c == 1) ? v.y : (c == 2) ? v.z : v.w;
      if ((bits >> 20) >= bA) {
        uint p = atomicAdd(&scnt, 1u);
        if (p < 4096) ents[p] = make_uint2(bits, base + c);
        else { uint q = atomicAdd(&ctrl[5], 1u); if (q < CAND_CAP) cand[q] = make_uint2(bits, base + c); }
      }
    }
  }
  __syncthreads();
  uint m = min(scnt, 4096u);
  if (threadIdx.x == 0) sbase = atomicAdd(&ctrl[5], m);
  __syncthreads();
  for (uint i = threadIdx.x; i < m; i += 256) {
    uint p = sbase + i;
    if (p < CAND_CAP) cand[p] = ents[i];
  }
}

// ---------------- fused refinement over the candidate list (1 block) ----------------
__global__ __launch_bounds__(1024) void refine(uint* __restrict__ ctrl, const uint2* __restrict__ cand,
                                               uint* __restrict__ tiekeep)
{
  __shared__ uint h[4096];
  __shared__ uint ssum[1024];
  __shared__ uint s_scal[8];    // [0]=bB [1]=C_B [2]=tau [3]=nt [4]=tiecnt
  __shared__ uint s_tie[2048];
  int t = threadIdx.x;
  uint nC = min(ctrl[5], (uint)CAND_CAP);
  uint bA = ctrl[1], C_A = ctrl[2];

  // phase 1: mid-12-bit hist over candidates inside bin bA
  for (int i = t; i < 4096; i += 1024) h[i] = 0;
  __syncthreads();
  for (uint i = t; i < nC; i += 1024) {
    uint2 e = cand[i];
    if ((e.x >> 20) == bA) atomicAdd(&h[(e.x >> 8) & 0xFFFu], 1u);
  }
  __syncthreads();
  {
    int hi = 4096 - 4 * t;
    uint s = 0;
    for (int b = hi - 4; b < hi; ++b) s += h[b];
    ssum[t] = s;
  }
  __syncthreads();
  if (t == 0) {
    uint C = C_A;
    int tc = 1023;
    for (int i = 0; i < 1024; ++i) {
      if (C + ssum[i] >= TOTAL_K) { tc = i; break; }
      C += ssum[i];
    }
    int top = 4096 - 4 * tc - 1;
    uint bin = (uint)(top - 3);
    for (int b = top; b >= top - 3; --b) {
      uint c = h[b];
      if (C + c >= TOTAL_K) { bin = (uint)b; break; }
      C += c;
    }
    s_scal[0] = bin; s_scal[1] = C;
    ctrl[3] = bin;   ctrl[4] = C;
  }
  __syncthreads();
  uint target = (bA << 12) | s_scal[0];
  uint C_B = s_scal[1];

  // phase 2: low-8-bit hist over top24 == target
  for (int i = t; i < 256; i += 1024) h[i] = 0;
  __syncthreads();
  for (uint i = t; i < nC; i += 1024) {
    uint2 e = cand[i];
    if ((e.x >> 8) == target) atomicAdd(&h[e.x & 0xFFu], 1u);
  }
  __syncthreads();
  if (t == 0) {
    uint need = TOTAL_K - C_B;   // >= 1
    uint c = 0, v = 0, cgt = 0;
    for (int b = 255; b >= 0; --b) {
      if (c + h[b] >= need) { v = (uint)b; cgt = c; break; }
      c += h[b];
    }
    uint tau = (target << 8) | v;
    s_scal[2] = tau; s_scal[3] = need - cgt;
    ctrl[6] = tau;   ctrl[7] = need - cgt;
    s_scal[4] = 0;
  }
  __syncthreads();

  // phase 3: stable tie selection (smallest flat indices kept)
  uint tau = s_scal[2];
  for (uint i = t; i < nC; i += 1024)
    if (cand[i].x == tau) { uint p = atomicAdd(&s_scal[4], 1u); if (p < 2048) s_tie[p] = cand[i].y; }
  __syncthreads();
  uint m = min(s_scal[4], 2048u);
  uint nt = s_scal[3];
  for (uint i = t; i < m; i += 1024) {
    uint my = s_tie[i];
    uint rank = 0;
    for (uint j = 0; j < m; ++j) rank += (s_tie[j] < my) ? 1u : 0u;
    if (rank < nt) tiekeep[rank] = my;
  }
}

// ---------------- scatter kept values into zeroed z + rowcnt ----------------
__global__ __launch_bounds__(256) void scatter_kept(const uint* __restrict__ ctrl, const uint2* __restrict__ cand,
                                                    const uint* __restrict__ tiekeep,
                                                    float* __restrict__ z, uint* __restrict__ rowcnt)
{
  uint nC = min(ctrl[5], (uint)CAND_CAP);
  uint i = blockIdx.x * 256 + threadIdx.x;
  if (i >= nC) return;
  uint tau = ctrl[6], nt = ctrl[7];
  uint2 e = cand[i];
  bool keep = e.x > tau;
  if (!keep && e.x == tau) {
    for (uint j = 0; j < nt; ++j)
      if (tiekeep[j] == e.y) { keep = true; break; }
  }
  if (keep) {
    z[e.y] = __uint_as_float(e.x);
    atomicAdd(&rowcnt[e.y >> 14], 1u);
  }
}

// ---------------- prefix sum over row counts ----------------
__global__ __launch_bounds__(256) void prefix_rows(const uint* __restrict__ rowcnt,
                                                   uint* __restrict__ rowoff, uint* __restrict__ cursor)
{
  __shared__ uint s[256];
  __shared__ uint pref[257];
  int t = threadIdx.x;
  uint loc[16], sum = 0;
#pragma unroll
  for (int r = 0; r < 16; ++r) { loc[r] = rowcnt[t * 16 + r]; sum += loc[r]; }
  s[t] = sum;
  __syncthreads();
  if (t == 0) {
    uint a = 0;
    for (int i = 0; i < 256; ++i) { pref[i] = a; a += s[i]; }
    pref[256] = a;
  }
  __syncthreads();
  uint off = pref[t];
#pragma unroll
  for (int r = 0; r < 16; ++r) {
    rowoff[t * 16 + r] = off;
    cursor[t * 16 + r] = off;
    off += loc[r];
  }
  if (t == 255) rowoff[BATCH] = off;
}

// ---------------- group kept entries by row ----------------
__global__ __launch_bounds__(256) void group_pass(const uint* __restrict__ ctrl, const uint2* __restrict__ cand,
                                                  const uint* __restrict__ tiekeep,
                                                  uint* __restrict__ cursor, uint2* __restrict__ grouped)
{
  uint nC = min(ctrl[5], (uint)CAND_CAP);
  uint i = blockIdx.x * 256 + threadIdx.x;
  if (i >= nC) return;
  uint tau = ctrl[6], nt = ctrl[7];
  uint2 e = cand[i];
  bool keep = e.x > tau;
  if (!keep && e.x == tau) {
    for (uint j = 0; j < nt; ++j)
      if (tiekeep[j] == e.y) { keep = true; break; }
  }
  if (keep) {
    uint p = atomicAdd(&cursor[e.y >> 14], 1u);
    grouped[p] = make_uint2(e.y, e.x);   // (flat idx, bits)
  }
}

// ---------------- sparse decode ----------------
__global__ __launch_bounds__(256) void decode_kernel(const uint* __restrict__ rowoff, const uint2* __restrict__ grouped,
                                                     const float* __restrict__ Wdec, const float* __restrict__ bdec,
                                                     float* __restrict__ xhat)
{
  int r = blockIdx.x;
  int t = threadIdx.x;
  uint beg = rowoff[r], end = rowoff[r + 1];
  float a0 = bdec[t], a1 = bdec[t + 256], a2 = bdec[t + 512];
  __shared__ uint2 ch[128];
  for (uint c0 = beg; c0 < end; c0 += 128) {
    uint m = min(128u, end - c0);
    if (t < (int)m) ch[t] = grouped[c0 + t];
    __syncthreads();
    for (uint e = 0; e < m; ++e) {
      uint2 en = ch[e];
      float v = __uint_as_float(en.y);
      uint j = en.x & (D_SAE - 1);
      const float* wr = Wdec + (size_t)j * D_IN;
      a0 = fmaf(v, wr[t], a0);
      a1 = fmaf(v, wr[t + 256], a1);
      a2 = fmaf(v, wr[t + 512], a2);
    }
    __syncthreads();
  }
  float* out = xhat + (size_t)r * D_IN;
  out[t] = a0; out[t + 256] = a1; out[t + 512] = a2;
}

extern "C" void kernel_launch(void* const* d_in, const int* in_sizes, int n_in,
                              void* d_out, int out_size, void* d_ws, size_t ws_size,
                              hipStream_t stream)
{
  const float* x    = (const float*)d_in[0];
  const float* Wenc = (const float*)d_in[1];
  const float* benc = (const float*)d_in[2];
  const float* Wdec = (const float*)d_in[3];
  const float* bdec = (const float*)d_in[4];

  float* xhat = (float*)d_out;                        // [4096, 768]
  float* z    = (float*)d_out + (size_t)BATCH * D_IN; // [4096, 16384]; holds pre, then zeroed+scattered

  char* ws = (char*)d_ws;
  uint*  ctrl    = (uint*)(ws + CTRL_OFF);
  uint*  histA   = (uint*)(ws + HISTA_OFF);
  uint*  rowcnt  = (uint*)(ws + ROWCNT_OFF);
  uint*  rowoff  = (uint*)(ws + ROWOFF_OFF);
  uint*  cursor  = (uint*)(ws + CURSOR_OFF);
  uint*  tiekeep = (uint*)(ws + TIEKEEP_OFF);
  uint2* cand    = (uint2*)(ws + CAND_OFF);
  uint2* grouped = (uint2*)(ws + GROUPED_OFF);

  (void)hipMemsetAsync(d_ws, 0, ZERO_BYTES, stream);

  dim3 ggrid(D_SAE / 128, BATCH / 128);
  enc_gemm<<<ggrid, 256, 0, stream>>>(x, Wenc, benc, bdec, z, histA);

  select_bin<<<1, 256, 0, stream>>>(histA, ctrl);
  collect_ge<<<1024, 256, 0, stream>>>((const uint*)z, ctrl, cand);
  refine<<<1, 1024, 0, stream>>>(ctrl, cand, tiekeep);

  (void)hipMemsetAsync(z, 0, NPRE * sizeof(float), stream);
  scatter_kept<<<CAND_CAP / 256, 256, 0, stream>>>(ctrl, cand, tiekeep, z, rowcnt);
  prefix_rows<<<1, 256, 0, stream>>>(rowcnt, rowoff, cursor);
  group_pass<<<CAND_CAP / 256, 256, 0, stream>>>(ctrl, cand, tiekeep, cursor, grouped);
  decode_kernel<<<BATCH, 256, 0, stream>>>(rowoff, grouped, Wdec, bdec, xhat);
}

// Round 6
// 1652.709 us; speedup vs baseline: 1.0247x; 1.0247x over previous
//
#include <hip/hip_runtime.h>

typedef unsigned int uint;

constexpr int D_IN   = 768;
constexpr int D_SAE  = 16384;   // 2^14
constexpr int BATCH  = 4096;
constexpr int TOTAL_K = 64 * 4096;              // 262144
constexpr size_t NPRE = (size_t)BATCH * D_SAE;  // 67,108,864

// ---------------- workspace layout (bytes) ----------------
// ctrl[1]=bA ctrl[2]=C_A ctrl[3]=bB ctrl[4]=C_B ctrl[5]=nCand ctrl[6]=tau ctrl[7]=nt
constexpr size_t CTRL_OFF    = 0;                         // 16 uints
constexpr size_t HISTA_OFF   = 64;                        // 4096 uints
constexpr size_t ROWCNT_OFF  = HISTA_OFF + 4096 * 4;      // BATCH uints
constexpr size_t ZERO_BYTES  = ROWCNT_OFF + BATCH * 4;    // memset region end
constexpr size_t ROWOFF_OFF  = ZERO_BYTES;                // BATCH+1 uints (pad)
constexpr size_t CURSOR_OFF  = ROWOFF_OFF + (BATCH + 64) * 4;
constexpr size_t TIEKEEP_OFF = CURSOR_OFF + BATCH * 4;    // 2048 uints
constexpr int    CAND_CAP    = 655360;                    // ~2x expected ~312K
constexpr size_t CAND_OFF    = TIEKEEP_OFF + 2048 * 4;    // uint2 * CAND_CAP (5 MB)
constexpr size_t GROUPED_OFF = CAND_OFF + (size_t)CAND_CAP * 8;  // uint2*(TOTAL_K+2048)

// ---------------- encoder GEMM: pre = relu((x - b_dec) @ W_enc + b_enc) ----------------
// 128x256 block tile, 8x16 per thread. Epilogue builds the 4096-bin top-12-bit
// histogram in reused LDS.
// NOTE: each output's accumulation order (k0 ascending by 32, k ascending, single
// fmaf chain) is bitwise-identical to prior rounds — the global top-k boundary
// depends on it. Tile-shape changes don't alter the per-output chain.
__global__ __launch_bounds__(256, 2) void enc_gemm(
    const float* __restrict__ x, const float* __restrict__ W,
    const float* __restrict__ benc, const float* __restrict__ bdec,
    float* __restrict__ pre, uint* __restrict__ histA)
{
  __shared__ float smem[12544];     // xs[32][132] | wsh[32][260]; reused as hist[4096]
  float* xs  = smem;                // xs: element (k,row) at k*132+row
  float* wsh = smem + 4224;         // wsh: element (k,col) at k*260+col
  const int tid = threadIdx.x;
  const int ty = tid >> 4, tx = tid & 15;
  const int m0 = blockIdx.y * 128;
  const int n0 = blockIdx.x * 256;

  float acc[8][16];
#pragma unroll
  for (int i = 0; i < 8; ++i)
#pragma unroll
    for (int j = 0; j < 16; ++j) acc[i][j] = 0.f;

  for (int k0 = 0; k0 < D_IN; k0 += 32) {
    // x tile: 128 rows x 32 k (subtract b_dec on the way in)
#pragma unroll
    for (int r = 0; r < 4; ++r) {
      int chunk = tid + 256 * r;
      int row = chunk >> 3, c4 = (chunk & 7) * 4;
      float4 v  = *(const float4*)(x + (size_t)(m0 + row) * D_IN + k0 + c4);
      float4 bd = *(const float4*)(bdec + k0 + c4);
      xs[(c4 + 0) * 132 + row] = v.x - bd.x;
      xs[(c4 + 1) * 132 + row] = v.y - bd.y;
      xs[(c4 + 2) * 132 + row] = v.z - bd.z;
      xs[(c4 + 3) * 132 + row] = v.w - bd.w;
    }
    // W tile: 32 k x 256 cols
#pragma unroll
    for (int r = 0; r < 8; ++r) {
      int chunk = tid + 256 * r;            // 0..2047
      int k = chunk >> 6, col = (chunk & 63) * 4;
      float4 v = *(const float4*)(W + (size_t)(k0 + k) * D_SAE + n0 + col);
      *(float4*)&wsh[k * 260 + col] = v;
    }
    __syncthreads();
#pragma unroll 4
    for (int k = 0; k < 32; ++k) {
      float a[8], b[16];
      *(float4*)&a[0] = *(const float4*)&xs[k * 132 + ty * 4];
      *(float4*)&a[4] = *(const float4*)&xs[k * 132 + 64 + ty * 4];
      *(float4*)&b[0]  = *(const float4*)&wsh[k * 260 +   0 + tx * 4];
      *(float4*)&b[4]  = *(const float4*)&wsh[k * 260 +  64 + tx * 4];
      *(float4*)&b[8]  = *(const float4*)&wsh[k * 260 + 128 + tx * 4];
      *(float4*)&b[12] = *(const float4*)&wsh[k * 260 + 192 + tx * 4];
#pragma unroll
      for (int i = 0; i < 8; ++i)
#pragma unroll
        for (int j = 0; j < 16; ++j)
          acc[i][j] = fmaf(a[i], b[j], acc[i][j]);
    }
    __syncthreads();
  }

  // epilogue: + b_enc, relu, store, LDS histogram of top-12 bits
  uint* h = (uint*)smem;
  for (int i = tid; i < 4096; i += 256) h[i] = 0;
  __syncthreads();
#pragma unroll
  for (int i = 0; i < 8; ++i) {
    int row = m0 + ((i < 4) ? (ty * 4 + i) : (64 + ty * 4 + i - 4));
    float* outr = pre + (size_t)row * D_SAE + n0;
#pragma unroll
    for (int g = 0; g < 4; ++g) {
      int cb = 64 * g + tx * 4;
      float4 be = *(const float4*)(benc + n0 + cb);
      float4 o;
      o.x = fmaxf(acc[i][g * 4 + 0] + be.x, 0.f);
      o.y = fmaxf(acc[i][g * 4 + 1] + be.y, 0.f);
      o.z = fmaxf(acc[i][g * 4 + 2] + be.z, 0.f);
      o.w = fmaxf(acc[i][g * 4 + 3] + be.w, 0.f);
      *(float4*)(outr + cb) = o;
      uint bx = __float_as_uint(o.x), by = __float_as_uint(o.y);
      uint bz = __float_as_uint(o.z), bw = __float_as_uint(o.w);
      if (bx) atomicAdd(&h[bx >> 20], 1u);
      if (by) atomicAdd(&h[by >> 20], 1u);
      if (bz) atomicAdd(&h[bz >> 20], 1u);
      if (bw) atomicAdd(&h[bw >> 20], 1u);
    }
  }
  __syncthreads();
  for (int i = tid; i < 4096; i += 256) {
    uint c = h[i];
    if (c) atomicAdd(&histA[i], c);
  }
}

// ---------------- stage-0 crossing-bin search ----------------
__global__ __launch_bounds__(256) void select_bin(const uint* __restrict__ hist, uint* ctrl)
{
  __shared__ uint ssum[256];
  int t = threadIdx.x;
  int hi = 4096 - 16 * t;
  uint sum = 0;
  for (int b = hi - 16; b < hi; ++b) sum += hist[b];
  ssum[t] = sum;
  __syncthreads();
  if (t == 0) {
    uint C = 0;
    int tc = 255;
    for (int i = 0; i < 256; ++i) {
      if (C + ssum[i] >= TOTAL_K) { tc = i; break; }
      C += ssum[i];
    }
    int top = 4096 - 16 * tc - 1;
    uint bin = (uint)(top - 15);
    for (int b = top; b >= top - 15; --b) {
      uint c = hist[b];
      if (C + c >= TOTAL_K) { bin = (uint)b; break; }
      C += c;
    }
    ctrl[1] = bin;   // bA
    ctrl[2] = C;     // C_A = count strictly above bin bA
  }
}

// ---------------- collect ALL elements with top12 >= bA; zero pre in place ----------------
__global__ __launch_bounds__(256) void collect_ge(uint* __restrict__ pre, uint* __restrict__ ctrl,
                                                  uint2* __restrict__ cand)
{
  __shared__ uint2 ents[4096];
  __shared__ uint scnt, sbase;
  if (threadIdx.x == 0) scnt = 0;
  __syncthreads();
  uint bA = ctrl[1];
  size_t n4 = NPRE / 4;
  size_t stride = (size_t)gridDim.x * 256;
  const uint4 zero4 = make_uint4(0, 0, 0, 0);
  for (size_t i = (size_t)blockIdx.x * 256 + threadIdx.x; i < n4; i += stride) {
    uint4 v = ((const uint4*)pre)[i];
    ((uint4*)pre)[i] = zero4;          // z := 0; kept entries re-scattered later
    uint base = (uint)(i * 4);
#pragma unroll
    for (int c = 0; c < 4; ++c) {
      uint bits = (c == 0) ? v.x : (c == 1) ? v.y : (c == 2) ? v.z : v.w;
      if ((bits >> 20) >= bA) {
        uint p = atomicAdd(&scnt, 1u);
        if (p < 4096) ents[p] = make_uint2(bits, base + c);
        else { uint q = atomicAdd(&ctrl[5], 1u); if (q < CAND_CAP) cand[q] = make_uint2(bits, base + c); }
      }
    }
  }
  __syncthreads();
  uint m = min(scnt, 4096u);
  if (threadIdx.x == 0) sbase = atomicAdd(&ctrl[5], m);
  __syncthreads();
  for (uint i = threadIdx.x; i < m; i += 256) {
    uint p = sbase + i;
    if (p < CAND_CAP) cand[p] = ents[i];
  }
}

// ---------------- fused refinement over the candidate list (1 block) ----------------
__global__ __launch_bounds__(1024) void refine(uint* __restrict__ ctrl, const uint2* __restrict__ cand,
                                               uint* __restrict__ tiekeep)
{
  __shared__ uint h[4096];
  __shared__ uint ssum[1024];
  __shared__ uint s_scal[8];    // [0]=bB [1]=C_B [2]=tau [3]=nt [4]=tiecnt
  __shared__ uint s_tie[2048];
  int t = threadIdx.x;
  uint nC = min(ctrl[5], (uint)CAND_CAP);
  uint bA = ctrl[1], C_A = ctrl[2];

  // phase 1: mid-12-bit hist over candidates inside bin bA
  for (int i = t; i < 4096; i += 1024) h[i] = 0;
  __syncthreads();
  for (uint i = t; i < nC; i += 1024) {
    uint2 e = cand[i];
    if ((e.x >> 20) == bA) atomicAdd(&h[(e.x >> 8) & 0xFFFu], 1u);
  }
  __syncthreads();
  {
    int hi = 4096 - 4 * t;
    uint s = 0;
    for (int b = hi - 4; b < hi; ++b) s += h[b];
    ssum[t] = s;
  }
  __syncthreads();
  if (t == 0) {
    uint C = C_A;
    int tc = 1023;
    for (int i = 0; i < 1024; ++i) {
      if (C + ssum[i] >= TOTAL_K) { tc = i; break; }
      C += ssum[i];
    }
    int top = 4096 - 4 * tc - 1;
    uint bin = (uint)(top - 3);
    for (int b = top; b >= top - 3; --b) {
      uint c = h[b];
      if (C + c >= TOTAL_K) { bin = (uint)b; break; }
      C += c;
    }
    s_scal[0] = bin; s_scal[1] = C;
    ctrl[3] = bin;   ctrl[4] = C;
  }
  __syncthreads();
  uint target = (bA << 12) | s_scal[0];
  uint C_B = s_scal[1];

  // phase 2: low-8-bit hist over top24 == target
  for (int i = t; i < 256; i += 1024) h[i] = 0;
  __syncthreads();
  for (uint i = t; i < nC; i += 1024) {
    uint2 e = cand[i];
    if ((e.x >> 8) == target) atomicAdd(&h[e.x & 0xFFu], 1u);
  }
  __syncthreads();
  if (t == 0) {
    uint need = TOTAL_K - C_B;   // >= 1
    uint c = 0, v = 0, cgt = 0;
    for (int b = 255; b >= 0; --b) {
      if (c + h[b] >= need) { v = (uint)b; cgt = c; break; }
      c += h[b];
    }
    uint tau = (target << 8) | v;
    s_scal[2] = tau; s_scal[3] = need - cgt;
    ctrl[6] = tau;   ctrl[7] = need - cgt;
    s_scal[4] = 0;
  }
  __syncthreads();

  // phase 3: stable tie selection (smallest flat indices kept)
  uint tau = s_scal[2];
  for (uint i = t; i < nC; i += 1024)
    if (cand[i].x == tau) { uint p = atomicAdd(&s_scal[4], 1u); if (p < 2048) s_tie[p] = cand[i].y; }
  __syncthreads();
  uint m = min(s_scal[4], 2048u);
  uint nt = s_scal[3];
  for (uint i = t; i < m; i += 1024) {
    uint my = s_tie[i];
    uint rank = 0;
    for (uint j = 0; j < m; ++j) rank += (s_tie[j] < my) ? 1u : 0u;
    if (rank < nt) tiekeep[rank] = my;
  }
}

// ---------------- scatter kept values into zeroed z + rowcnt ----------------
__global__ __launch_bounds__(256) void scatter_kept(const uint* __restrict__ ctrl, const uint2* __restrict__ cand,
                                                    const uint* __restrict__ tiekeep,
                                                    float* __restrict__ z, uint* __restrict__ rowcnt)
{
  uint nC = min(ctrl[5], (uint)CAND_CAP);
  uint i = blockIdx.x * 256 + threadIdx.x;
  if (i >= nC) return;
  uint tau = ctrl[6], nt = ctrl[7];
  uint2 e = cand[i];
  bool keep = e.x > tau;
  if (!keep && e.x == tau) {
    for (uint j = 0; j < nt; ++j)
      if (tiekeep[j] == e.y) { keep = true; break; }
  }
  if (keep) {
    z[e.y] = __uint_as_float(e.x);
    atomicAdd(&rowcnt[e.y >> 14], 1u);
  }
}

// ---------------- prefix sum over row counts ----------------
__global__ __launch_bounds__(256) void prefix_rows(const uint* __restrict__ rowcnt,
                                                   uint* __restrict__ rowoff, uint* __restrict__ cursor)
{
  __shared__ uint s[256];
  __shared__ uint pref[257];
  int t = threadIdx.x;
  uint loc[16], sum = 0;
#pragma unroll
  for (int r = 0; r < 16; ++r) { loc[r] = rowcnt[t * 16 + r]; sum += loc[r]; }
  s[t] = sum;
  __syncthreads();
  if (t == 0) {
    uint a = 0;
    for (int i = 0; i < 256; ++i) { pref[i] = a; a += s[i]; }
    pref[256] = a;
  }
  __syncthreads();
  uint off = pref[t];
#pragma unroll
  for (int r = 0; r < 16; ++r) {
    rowoff[t * 16 + r] = off;
    cursor[t * 16 + r] = off;
    off += loc[r];
  }
  if (t == 255) rowoff[BATCH] = off;
}

// ---------------- group kept entries by row ----------------
__global__ __launch_bounds__(256) void group_pass(const uint* __restrict__ ctrl, const uint2* __restrict__ cand,
                                                  const uint* __restrict__ tiekeep,
                                                  uint* __restrict__ cursor, uint2* __restrict__ grouped)
{
  uint nC = min(ctrl[5], (uint)CAND_CAP);
  uint i = blockIdx.x * 256 + threadIdx.x;
  if (i >= nC) return;
  uint tau = ctrl[6], nt = ctrl[7];
  uint2 e = cand[i];
  bool keep = e.x > tau;
  if (!keep && e.x == tau) {
    for (uint j = 0; j < nt; ++j)
      if (tiekeep[j] == e.y) { keep = true; break; }
  }
  if (keep) {
    uint p = atomicAdd(&cursor[e.y >> 14], 1u);
    grouped[p] = make_uint2(e.y, e.x);   // (flat idx, bits)
  }
}

// ---------------- sparse decode ----------------
__global__ __launch_bounds__(256) void decode_kernel(const uint* __restrict__ rowoff, const uint2* __restrict__ grouped,
                                                     const float* __restrict__ Wdec, const float* __restrict__ bdec,
                                                     float* __restrict__ xhat)
{
  int r = blockIdx.x;
  int t = threadIdx.x;
  uint beg = rowoff[r], end = rowoff[r + 1];
  float a0 = bdec[t], a1 = bdec[t + 256], a2 = bdec[t + 512];
  __shared__ uint2 ch[128];
  for (uint c0 = beg; c0 < end; c0 += 128) {
    uint m = min(128u, end - c0);
    if (t < (int)m) ch[t] = grouped[c0 + t];
    __syncthreads();
    for (uint e = 0; e < m; ++e) {
      uint2 en = ch[e];
      float v = __uint_as_float(en.y);
      uint j = en.x & (D_SAE - 1);
      const float* wr = Wdec + (size_t)j * D_IN;
      a0 = fmaf(v, wr[t], a0);
      a1 = fmaf(v, wr[t + 256], a1);
      a2 = fmaf(v, wr[t + 512], a2);
    }
    __syncthreads();
  }
  float* out = xhat + (size_t)r * D_IN;
  out[t] = a0; out[t + 256] = a1; out[t + 512] = a2;
}

extern "C" void kernel_launch(void* const* d_in, const int* in_sizes, int n_in,
                              void* d_out, int out_size, void* d_ws, size_t ws_size,
                              hipStream_t stream)
{
  const float* x    = (const float*)d_in[0];
  const float* Wenc = (const float*)d_in[1];
  const float* benc = (const float*)d_in[2];
  const float* Wdec = (const float*)d_in[3];
  const float* bdec = (const float*)d_in[4];

  float* xhat = (float*)d_out;                        // [4096, 768]
  float* z    = (float*)d_out + (size_t)BATCH * D_IN; // [4096, 16384]; holds pre, then zeroed+scattered

  char* ws = (char*)d_ws;
  uint*  ctrl    = (uint*)(ws + CTRL_OFF);
  uint*  histA   = (uint*)(ws + HISTA_OFF);
  uint*  rowcnt  = (uint*)(ws + ROWCNT_OFF);
  uint*  rowoff  = (uint*)(ws + ROWOFF_OFF);
  uint*  cursor  = (uint*)(ws + CURSOR_OFF);
  uint*  tiekeep = (uint*)(ws + TIEKEEP_OFF);
  uint2* cand    = (uint2*)(ws + CAND_OFF);
  uint2* grouped = (uint2*)(ws + GROUPED_OFF);

  (void)hipMemsetAsync(d_ws, 0, ZERO_BYTES, stream);

  dim3 ggrid(D_SAE / 256, BATCH / 128);
  enc_gemm<<<ggrid, 256, 0, stream>>>(x, Wenc, benc, bdec, z, histA);

  select_bin<<<1, 256, 0, stream>>>(histA, ctrl);
  collect_ge<<<1024, 256, 0, stream>>>((uint*)z, ctrl, cand);
  refine<<<1, 1024, 0, stream>>>(ctrl, cand, tiekeep);

  scatter_kept<<<CAND_CAP / 256, 256, 0, stream>>>(ctrl, cand, tiekeep, z, rowcnt);
  prefix_rows<<<1, 256, 0, stream>>>(rowcnt, rowoff, cursor);
  group_pass<<<CAND_CAP / 256, 256, 0, stream>>>(ctrl, cand, tiekeep, cursor, grouped);
  decode_kernel<<<BATCH, 256, 0, stream>>>(rowoff, grouped, Wdec, bdec, xhat);
}

// Round 7
// 1006.594 us; speedup vs baseline: 1.6824x; 1.6419x over previous
//
#include <hip/hip_runtime.h>

typedef unsigned int uint;
typedef unsigned short ushort_t;
typedef short bf16x8 __attribute__((ext_vector_type(8)));
typedef float f32x4 __attribute__((ext_vector_type(4)));

constexpr int D_IN   = 768;
constexpr int D_SAE  = 16384;   // 2^14
constexpr int BATCH  = 4096;
constexpr int TOTAL_K = 64 * 4096;              // 262144
constexpr size_t NPRE = (size_t)BATCH * D_SAE;  // 67,108,864

// ---------------- workspace layout (bytes) ----------------
// ctrl[1]=bA_exact ctrl[2]=C_A_exact ctrl[3]=thr16(bf16 bits) ctrl[5]=nCand
// ctrl[6]=tau ctrl[7]=nt
constexpr size_t CTRL_OFF    = 0;                          // 16 uints
constexpr size_t HISTA_OFF   = 64;                         // 8192 uints (13-bit approx hist)
constexpr size_t HISTB_OFF   = HISTA_OFF + 8192 * 4;       // 4096 uints (12-bit exact hist)
constexpr size_t ROWCNT_OFF  = HISTB_OFF + 4096 * 4;       // BATCH uints
constexpr size_t ZERO_BYTES  = ROWCNT_OFF + BATCH * 4;     // memset region end
constexpr size_t ROWOFF_OFF  = ZERO_BYTES;                 // BATCH+1 uints (pad)
constexpr size_t CURSOR_OFF  = ROWOFF_OFF + (BATCH + 64) * 4;
constexpr size_t TIEKEEP_OFF = CURSOR_OFF + BATCH * 4;     // 2048 uints
constexpr int    CAND_CAP    = 1048576;                    // ~2x worst-case band
constexpr size_t CAND_OFF    = TIEKEEP_OFF + 2048 * 4;     // uint2 * CAND_CAP (8 MB)
constexpr size_t GROUPED_OFF = CAND_OFF + (size_t)CAND_CAP * 8;  // uint2*(TOTAL_K+2048)

__device__ __forceinline__ ushort_t f2bf(float f) {        // RNE fp32->bf16 (finite inputs)
  uint u = __float_as_uint(f);
  return (ushort_t)((u + 0x7FFFu + ((u >> 16) & 1u)) >> 16);
}

// ---------------- prep: xc_bf16 = bf16(x - b_dec) ----------------
__global__ __launch_bounds__(256) void prep_x(const float* __restrict__ x,
                                              const float* __restrict__ bdec,
                                              ushort_t* __restrict__ xc)
{
  int i = blockIdx.x * 256 + threadIdx.x;     // one float4 per thread
  int k4 = i % (D_IN / 4), r = i / (D_IN / 4);
  float4 v  = *(const float4*)(x + (size_t)r * D_IN + k4 * 4);
  float4 bd = *(const float4*)(bdec + k4 * 4);
  ushort4 s;
  s.x = f2bf(v.x - bd.x); s.y = f2bf(v.y - bd.y);
  s.z = f2bf(v.z - bd.z); s.w = f2bf(v.w - bd.w);
  *(ushort4*)(xc + (size_t)r * D_IN + k4 * 4) = s;
}

// ---------------- transpose W_enc -> WT_f32 [D_SAE][D_IN] + WT_bf16 ----------------
__global__ __launch_bounds__(256) void transpose_w(const float* __restrict__ W,
                                                   float* __restrict__ wtf,
                                                   ushort_t* __restrict__ wtb)
{
  __shared__ float t[64][65];
  int j0 = blockIdx.x * 64;    // D_SAE block
  int k0 = blockIdx.y * 64;    // D_IN block
  int tx = threadIdx.x & 15, ty = threadIdx.x >> 4;
#pragma unroll
  for (int rr = 0; rr < 4; ++rr) {
    float4 v = *(const float4*)(W + (size_t)(k0 + ty + 16 * rr) * D_SAE + j0 + tx * 4);
    t[tx * 4 + 0][ty + 16 * rr] = v.x;
    t[tx * 4 + 1][ty + 16 * rr] = v.y;
    t[tx * 4 + 2][ty + 16 * rr] = v.z;
    t[tx * 4 + 3][ty + 16 * rr] = v.w;
  }
  __syncthreads();
#pragma unroll
  for (int rr = 0; rr < 4; ++rr) {
    int j = j0 + ty + 16 * rr;
    float4 v;
    v.x = t[ty + 16 * rr][tx * 4 + 0];
    v.y = t[ty + 16 * rr][tx * 4 + 1];
    v.z = t[ty + 16 * rr][tx * 4 + 2];
    v.w = t[ty + 16 * rr][tx * 4 + 3];
    *(float4*)(wtf + (size_t)j * D_IN + k0 + tx * 4) = v;
    ushort4 s;
    s.x = f2bf(v.x); s.y = f2bf(v.y); s.z = f2bf(v.z); s.w = f2bf(v.w);
    *(ushort4*)(wtb + (size_t)j * D_IN + k0 + tx * 4) = s;
  }
}

// ---------------- bf16 MFMA GEMM: pre_b = bf16(relu(xc @ WT^T + b_enc)) ----------------
// 128x128 tile, 4 waves (2x2), each wave 64x64 = 4x4 frags of 16x16x32.
// A: xc[4096][768] bf16 row-major (k contiguous). B: wtb[16384][768] = W^T, so
// frag b = 8 contiguous k of one output column. C/D: col=lane&15, row=(lane>>4)*4+reg.
// Epilogue: store bf16 approx + 13-bin-octave LDS histogram (bin = bits16>>3).
__global__ __launch_bounds__(256, 3) void mfma_gemm(
    const ushort_t* __restrict__ xc, const ushort_t* __restrict__ wtb,
    const float* __restrict__ benc,
    ushort_t* __restrict__ pre_b, uint* __restrict__ histA)
{
  __shared__ char smem[36864];                 // As 18432 | Bs 18432 ; reused as hist[8192]
  ushort_t* As = (ushort_t*)smem;              // [128][72] (pad 8 -> 144B rows, 16B aligned)
  ushort_t* Bs = (ushort_t*)(smem + 18432);
  const int tid = threadIdx.x;
  const int m0 = blockIdx.y * 128;
  const int n0 = blockIdx.x * 128;
  const int lane = tid & 63;
  const int wave = tid >> 6;
  const int wr = wave >> 1, wc = wave & 1;
  const int l15 = lane & 15, l4 = lane >> 4;
  const int srow = tid >> 1, shalf = tid & 1;  // staging: row, 32-elem half

  f32x4 acc[4][4] = {};

  for (int k0 = 0; k0 < D_IN; k0 += 64) {
    {
      const uint4* sa = (const uint4*)(xc + (size_t)(m0 + srow) * D_IN + k0 + shalf * 32);
      uint4 a0 = sa[0], a1 = sa[1], a2 = sa[2], a3 = sa[3];
      const uint4* sb = (const uint4*)(wtb + (size_t)(n0 + srow) * D_IN + k0 + shalf * 32);
      uint4 b0 = sb[0], b1 = sb[1], b2 = sb[2], b3 = sb[3];
      uint4* da = (uint4*)(As + srow * 72 + shalf * 32);
      da[0] = a0; da[1] = a1; da[2] = a2; da[3] = a3;
      uint4* db = (uint4*)(Bs + srow * 72 + shalf * 32);
      db[0] = b0; db[1] = b1; db[2] = b2; db[3] = b3;
    }
    __syncthreads();
#pragma unroll
    for (int ks = 0; ks < 2; ++ks) {
      bf16x8 a[4], b[4];
#pragma unroll
      for (int m = 0; m < 4; ++m)
        a[m] = *(const bf16x8*)(As + (wr * 64 + m * 16 + l15) * 72 + ks * 32 + l4 * 8);
#pragma unroll
      for (int n = 0; n < 4; ++n)
        b[n] = *(const bf16x8*)(Bs + (wc * 64 + n * 16 + l15) * 72 + ks * 32 + l4 * 8);
#pragma unroll
      for (int m = 0; m < 4; ++m)
#pragma unroll
        for (int n = 0; n < 4; ++n)
          acc[m][n] = __builtin_amdgcn_mfma_f32_16x16x32_bf16(a[m], b[n], acc[m][n], 0, 0, 0);
    }
    __syncthreads();
  }

  // epilogue: +b_enc, relu, bf16 store, 8192-bin LDS hist of bf16 bits>>3
  uint* h = (uint*)smem;
  for (int i = tid; i < 8192; i += 256) h[i] = 0;
  __syncthreads();
#pragma unroll
  for (int m = 0; m < 4; ++m) {
#pragma unroll
    for (int n = 0; n < 4; ++n) {
      int col = n0 + wc * 64 + n * 16 + l15;
      float be = benc[col];
#pragma unroll
      for (int r = 0; r < 4; ++r) {
        int row = m0 + wr * 64 + m * 16 + l4 * 4 + r;
        float v = fmaxf(acc[m][n][r] + be, 0.f);
        ushort_t b16 = f2bf(v);
        pre_b[(size_t)row * D_SAE + col] = b16;
        if (b16) atomicAdd(&h[b16 >> 3], 1u);
      }
    }
  }
  __syncthreads();
  for (int i = tid; i < 8192; i += 256) {
    uint c = h[i];
    if (c) atomicAdd(&histA[i], c);
  }
}

// ---------------- approx-stage: conservative candidate threshold ----------------
// thr16 = bf16-bits threshold for {approx >= bin_lo(tau*) - 0.0625}; exact-vs-approx
// error is ~0.002 sigma (bf16 inputs) -> 30x margin.
__global__ __launch_bounds__(256) void select_thr(const uint* __restrict__ hist, uint* ctrl)
{
  __shared__ uint ssum[256];
  int t = threadIdx.x;
  int hi = 8192 - 32 * t;
  uint sum = 0;
  for (int b = hi - 32; b < hi; ++b) sum += hist[b];
  ssum[t] = sum;
  __syncthreads();
  if (t == 0) {
    uint C = 0;
    int tc = 255;
    for (int i = 0; i < 256; ++i) {
      if (C + ssum[i] >= TOTAL_K) { tc = i; break; }
      C += ssum[i];
    }
    int top = 8192 - 32 * tc - 1;
    uint bin = (uint)(top - 31);
    for (int b = top; b >= top - 31; --b) {
      uint c = hist[b];
      if (C + c >= TOTAL_K) { bin = (uint)b; break; }
      C += c;
    }
    float vlo = __uint_as_float(bin << 19);      // bin lower edge
    float tcf = vlo - 0.0625f;
    uint thr16;
    if (tcf <= 0.f) thr16 = 1u;
    else thr16 = (__float_as_uint(tcf) + 0xFFFFu) >> 16;
    if (thr16 == 0) thr16 = 1u;
    ctrl[3] = thr16;
  }
}

// ---------------- collect candidate indices: approx bits16 >= thr16 ----------------
__global__ __launch_bounds__(256) void collect_cands(const ushort_t* __restrict__ pre_b,
                                                     uint* __restrict__ ctrl, uint2* __restrict__ cand)
{
  __shared__ uint ents[4096];
  __shared__ uint scnt, sbase;
  if (threadIdx.x == 0) scnt = 0;
  __syncthreads();
  uint thr = ctrl[3];
  size_t n8 = NPRE / 8;
  size_t stride = (size_t)gridDim.x * 256;
  for (size_t i = (size_t)blockIdx.x * 256 + threadIdx.x; i < n8; i += stride) {
    uint4 v = ((const uint4*)pre_b)[i];
    uint base = (uint)(i * 8);
    uint vals[8] = {v.x & 0xFFFFu, v.x >> 16, v.y & 0xFFFFu, v.y >> 16,
                    v.z & 0xFFFFu, v.z >> 16, v.w & 0xFFFFu, v.w >> 16};
#pragma unroll
    for (int c = 0; c < 8; ++c) {
      if (vals[c] >= thr) {
        uint p = atomicAdd(&scnt, 1u);
        if (p < 4096) ents[p] = base + c;
        else { uint q = atomicAdd(&ctrl[5], 1u); if (q < CAND_CAP) cand[q] = make_uint2(0u, base + c); }
      }
    }
  }
  __syncthreads();
  uint m = min(scnt, 4096u);
  if (threadIdx.x == 0) sbase = atomicAdd(&ctrl[5], m);
  __syncthreads();
  for (uint i = threadIdx.x; i < m; i += 256) {
    uint p = sbase + i;
    if (p < CAND_CAP) cand[p] = make_uint2(0u, ents[i]);
  }
}

// ---------------- exact recompute: sequential k-ascending fmaf chain ----------------
// Bitwise-identical to the round-1..6 enc_gemm chain: acc = fmaf(x[k]-bd[k], w[k], acc),
// k = 0..767 in order; out = fmaxf(acc + b_enc, 0).
__global__ __launch_bounds__(256) void recompute(
    const float* __restrict__ x, const float* __restrict__ bdec,
    const float* __restrict__ benc, const float* __restrict__ wtf,
    const uint* __restrict__ ctrl, uint2* __restrict__ cand)
{
  uint nC = min(ctrl[5], (uint)CAND_CAP);
  uint i = blockIdx.x * 256 + threadIdx.x;
  if (i >= nC) return;
  uint idx = cand[i].y;
  uint r = idx >> 14, j = idx & (D_SAE - 1);
  const float* xr = x + (size_t)r * D_IN;
  const float* wr = wtf + (size_t)j * D_IN;
  float a = 0.f;
  for (int k = 0; k < D_IN; k += 4) {
    float4 xv = *(const float4*)(xr + k);
    float4 bd = *(const float4*)(bdec + k);
    float4 wv = *(const float4*)(wr + k);
    a = fmaf(xv.x - bd.x, wv.x, a);
    a = fmaf(xv.y - bd.y, wv.y, a);
    a = fmaf(xv.z - bd.z, wv.z, a);
    a = fmaf(xv.w - bd.w, wv.w, a);
  }
  float v = fmaxf(a + benc[j], 0.f);
  cand[i] = make_uint2(__float_as_uint(v), idx);
}

// ---------------- 12-bit hist of exact bits over candidates ----------------
__global__ __launch_bounds__(256) void hist_exact(const uint* __restrict__ ctrl,
                                                  const uint2* __restrict__ cand,
                                                  uint* __restrict__ histB)
{
  __shared__ uint h[4096];
  for (int i = threadIdx.x; i < 4096; i += 256) h[i] = 0;
  __syncthreads();
  uint nC = min(ctrl[5], (uint)CAND_CAP);
  uint stride = gridDim.x * 256;
  for (uint i = blockIdx.x * 256 + threadIdx.x; i < nC; i += stride)
    atomicAdd(&h[cand[i].x >> 20], 1u);
  __syncthreads();
  for (int i = threadIdx.x; i < 4096; i += 256) {
    uint c = h[i];
    if (c) atomicAdd(&histB[i], c);
  }
}

// ---------------- exact stage-0 crossing-bin search (writes ctrl[1], ctrl[2]) ----------------
__global__ __launch_bounds__(256) void select_bin(const uint* __restrict__ hist, uint* ctrl)
{
  __shared__ uint ssum[256];
  int t = threadIdx.x;
  int hi = 4096 - 16 * t;
  uint sum = 0;
  for (int b = hi - 16; b < hi; ++b) sum += hist[b];
  ssum[t] = sum;
  __syncthreads();
  if (t == 0) {
    uint C = 0;
    int tc = 255;
    for (int i = 0; i < 256; ++i) {
      if (C + ssum[i] >= TOTAL_K) { tc = i; break; }
      C += ssum[i];
    }
    int top = 4096 - 16 * tc - 1;
    uint bin = (uint)(top - 15);
    for (int b = top; b >= top - 15; --b) {
      uint c = hist[b];
      if (C + c >= TOTAL_K) { bin = (uint)b; break; }
      C += c;
    }
    ctrl[1] = bin;   // bA (exact)
    ctrl[2] = C;     // count strictly above bin bA
  }
}

// ---------------- fused refinement over the exact candidate list (1 block) ----------------
__global__ __launch_bounds__(1024) void refine(uint* __restrict__ ctrl, const uint2* __restrict__ cand,
                                               uint* __restrict__ tiekeep)
{
  __shared__ uint h[4096];
  __shared__ uint ssum[1024];
  __shared__ uint s_scal[8];    // [0]=bB [1]=C_B [2]=tau [3]=nt [4]=tiecnt
  __shared__ uint s_tie[2048];
  int t = threadIdx.x;
  uint nC = min(ctrl[5], (uint)CAND_CAP);
  uint bA = ctrl[1], C_A = ctrl[2];

  // phase 1: mid-12-bit hist over candidates inside bin bA
  for (int i = t; i < 4096; i += 1024) h[i] = 0;
  __syncthreads();
  for (uint i = t; i < nC; i += 1024) {
    uint2 e = cand[i];
    if ((e.x >> 20) == bA) atomicAdd(&h[(e.x >> 8) & 0xFFFu], 1u);
  }
  __syncthreads();
  {
    int hi = 4096 - 4 * t;
    uint s = 0;
    for (int b = hi - 4; b < hi; ++b) s += h[b];
    ssum[t] = s;
  }
  __syncthreads();
  if (t == 0) {
    uint C = C_A;
    int tc = 1023;
    for (int i = 0; i < 1024; ++i) {
      if (C + ssum[i] >= TOTAL_K) { tc = i; break; }
      C += ssum[i];
    }
    int top = 4096 - 4 * tc - 1;
    uint bin = (uint)(top - 3);
    for (int b = top; b >= top - 3; --b) {
      uint c = h[b];
      if (C + c >= TOTAL_K) { bin = (uint)b; break; }
      C += c;
    }
    s_scal[0] = bin; s_scal[1] = C;
  }
  __syncthreads();
  uint target = (bA << 12) | s_scal[0];
  uint C_B = s_scal[1];

  // phase 2: low-8-bit hist over top24 == target
  for (int i = t; i < 256; i += 1024) h[i] = 0;
  __syncthreads();
  for (uint i = t; i < nC; i += 1024) {
    uint2 e = cand[i];
    if ((e.x >> 8) == target) atomicAdd(&h[e.x & 0xFFu], 1u);
  }
  __syncthreads();
  if (t == 0) {
    uint need = TOTAL_K - C_B;   // >= 1
    uint c = 0, v = 0, cgt = 0;
    for (int b = 255; b >= 0; --b) {
      if (c + h[b] >= need) { v = (uint)b; cgt = c; break; }
      c += h[b];
    }
    uint tau = (target << 8) | v;
    s_scal[2] = tau; s_scal[3] = need - cgt;
    ctrl[6] = tau;   ctrl[7] = need - cgt;
    s_scal[4] = 0;
  }
  __syncthreads();

  // phase 3: stable tie selection (smallest flat indices kept)
  uint tau = s_scal[2];
  for (uint i = t; i < nC; i += 1024)
    if (cand[i].x == tau) { uint p = atomicAdd(&s_scal[4], 1u); if (p < 2048) s_tie[p] = cand[i].y; }
  __syncthreads();
  uint m = min(s_scal[4], 2048u);
  uint nt = s_scal[3];
  for (uint i = t; i < m; i += 1024) {
    uint my = s_tie[i];
    uint rank = 0;
    for (uint j = 0; j < m; ++j) rank += (s_tie[j] < my) ? 1u : 0u;
    if (rank < nt) tiekeep[rank] = my;
  }
}

// ---------------- scatter kept values into zeroed z + rowcnt ----------------
__global__ __launch_bounds__(256) void scatter_kept(const uint* __restrict__ ctrl, const uint2* __restrict__ cand,
                                                    const uint* __restrict__ tiekeep,
                                                    float* __restrict__ z, uint* __restrict__ rowcnt)
{
  uint nC = min(ctrl[5], (uint)CAND_CAP);
  uint i = blockIdx.x * 256 + threadIdx.x;
  if (i >= nC) return;
  uint tau = ctrl[6], nt = ctrl[7];
  uint2 e = cand[i];
  bool keep = e.x > tau;
  if (!keep && e.x == tau) {
    for (uint j = 0; j < nt; ++j)
      if (tiekeep[j] == e.y) { keep = true; break; }
  }
  if (keep) {
    z[e.y] = __uint_as_float(e.x);
    atomicAdd(&rowcnt[e.y >> 14], 1u);
  }
}

// ---------------- prefix sum over row counts ----------------
__global__ __launch_bounds__(256) void prefix_rows(const uint* __restrict__ rowcnt,
                                                   uint* __restrict__ rowoff, uint* __restrict__ cursor)
{
  __shared__ uint s[256];
  __shared__ uint pref[257];
  int t = threadIdx.x;
  uint loc[16], sum = 0;
#pragma unroll
  for (int r = 0; r < 16; ++r) { loc[r] = rowcnt[t * 16 + r]; sum += loc[r]; }
  s[t] = sum;
  __syncthreads();
  if (t == 0) {
    uint a = 0;
    for (int i = 0; i < 256; ++i) { pref[i] = a; a += s[i]; }
    pref[256] = a;
  }
  __syncthreads();
  uint off = pref[t];
#pragma unroll
  for (int r = 0; r < 16; ++r) {
    rowoff[t * 16 + r] = off;
    cursor[t * 16 + r] = off;
    off += loc[r];
  }
  if (t == 255) rowoff[BATCH] = off;
}

// ---------------- group kept entries by row ----------------
__global__ __launch_bounds__(256) void group_pass(const uint* __restrict__ ctrl, const uint2* __restrict__ cand,
                                                  const uint* __restrict__ tiekeep,
                                                  uint* __restrict__ cursor, uint2* __restrict__ grouped)
{
  uint nC = min(ctrl[5], (uint)CAND_CAP);
  uint i = blockIdx.x * 256 + threadIdx.x;
  if (i >= nC) return;
  uint tau = ctrl[6], nt = ctrl[7];
  uint2 e = cand[i];
  bool keep = e.x > tau;
  if (!keep && e.x == tau) {
    for (uint j = 0; j < nt; ++j)
      if (tiekeep[j] == e.y) { keep = true; break; }
  }
  if (keep) {
    uint p = atomicAdd(&cursor[e.y >> 14], 1u);
    grouped[p] = make_uint2(e.y, e.x);   // (flat idx, bits)
  }
}

// ---------------- sparse decode ----------------
__global__ __launch_bounds__(256) void decode_kernel(const uint* __restrict__ rowoff, const uint2* __restrict__ grouped,
                                                     const float* __restrict__ Wdec, const float* __restrict__ bdec,
                                                     float* __restrict__ xhat)
{
  int r = blockIdx.x;
  int t = threadIdx.x;
  uint beg = rowoff[r], end = rowoff[r + 1];
  float a0 = bdec[t], a1 = bdec[t + 256], a2 = bdec[t + 512];
  __shared__ uint2 ch[128];
  for (uint c0 = beg; c0 < end; c0 += 128) {
    uint m = min(128u, end - c0);
    if (t < (int)m) ch[t] = grouped[c0 + t];
    __syncthreads();
    for (uint e = 0; e < m; ++e) {
      uint2 en = ch[e];
      float v = __uint_as_float(en.y);
      uint j = en.x & (D_SAE - 1);
      const float* wr = Wdec + (size_t)j * D_IN;
      a0 = fmaf(v, wr[t], a0);
      a1 = fmaf(v, wr[t + 256], a1);
      a2 = fmaf(v, wr[t + 512], a2);
    }
    __syncthreads();
  }
  float* out = xhat + (size_t)r * D_IN;
  out[t] = a0; out[t + 256] = a1; out[t + 512] = a2;
}

extern "C" void kernel_launch(void* const* d_in, const int* in_sizes, int n_in,
                              void* d_out, int out_size, void* d_ws, size_t ws_size,
                              hipStream_t stream)
{
  const float* x    = (const float*)d_in[0];
  const float* Wenc = (const float*)d_in[1];
  const float* benc = (const float*)d_in[2];
  const float* Wdec = (const float*)d_in[3];
  const float* bdec = (const float*)d_in[4];

  // d_out: xhat [4096x768 f32] | z [4096x16384 f32]
  // Dead z-region reuse before z is written:
  //   pre_b  (bf16, 134 MB) at z+0
  //   WT_f32 (48 MB)        at z+134MB
  //   WT_bf16(24 MB)        at z+182MB
  // xc_bf16 (6 MB) lives in the xhat region (xhat written last, by decode).
  char* outb = (char*)d_out;
  float*    xhat  = (float*)outb;
  ushort_t* xc    = (ushort_t*)outb;
  char*     zb    = outb + (size_t)BATCH * D_IN * 4;
  float*    z     = (float*)zb;
  ushort_t* pre_b = (ushort_t*)zb;
  float*    wtf   = (float*)(zb + NPRE * 2);
  ushort_t* wtb   = (ushort_t*)(zb + NPRE * 2 + (size_t)D_SAE * D_IN * 4);

  char* ws = (char*)d_ws;
  uint*  ctrl    = (uint*)(ws + CTRL_OFF);
  uint*  histA   = (uint*)(ws + HISTA_OFF);
  uint*  histB   = (uint*)(ws + HISTB_OFF);
  uint*  rowcnt  = (uint*)(ws + ROWCNT_OFF);
  uint*  rowoff  = (uint*)(ws + ROWOFF_OFF);
  uint*  cursor  = (uint*)(ws + CURSOR_OFF);
  uint*  tiekeep = (uint*)(ws + TIEKEEP_OFF);
  uint2* cand    = (uint2*)(ws + CAND_OFF);
  uint2* grouped = (uint2*)(ws + GROUPED_OFF);

  (void)hipMemsetAsync(d_ws, 0, ZERO_BYTES, stream);

  prep_x<<<BATCH * D_IN / 4 / 256, 256, 0, stream>>>(x, bdec, xc);
  transpose_w<<<dim3(D_SAE / 64, D_IN / 64), 256, 0, stream>>>(Wenc, wtf, wtb);
  mfma_gemm<<<dim3(D_SAE / 128, BATCH / 128), 256, 0, stream>>>(xc, wtb, benc, pre_b, histA);

  select_thr<<<1, 256, 0, stream>>>(histA, ctrl);
  collect_cands<<<1024, 256, 0, stream>>>(pre_b, ctrl, cand);
  recompute<<<CAND_CAP / 256, 256, 0, stream>>>(x, bdec, benc, wtf, ctrl, cand);
  hist_exact<<<128, 256, 0, stream>>>(ctrl, cand, histB);
  select_bin<<<1, 256, 0, stream>>>(histB, ctrl);
  refine<<<1, 1024, 0, stream>>>(ctrl, cand, tiekeep);

  (void)hipMemsetAsync(z, 0, NPRE * 4, stream);
  scatter_kept<<<CAND_CAP / 256, 256, 0, stream>>>(ctrl, cand, tiekeep, z, rowcnt);
  prefix_rows<<<1, 256, 0, stream>>>(rowcnt, rowoff, cursor);
  group_pass<<<CAND_CAP / 256, 256, 0, stream>>>(ctrl, cand, tiekeep, cursor, grouped);
  decode_kernel<<<BATCH, 256, 0, stream>>>(rowoff, grouped, Wdec, bdec, xhat);
}

// Round 8
// 735.383 us; speedup vs baseline: 2.3028x; 1.3688x over previous
//
#include <hip/hip_runtime.h>

typedef unsigned int uint;
typedef unsigned short ushort_t;
typedef short bf16x8 __attribute__((ext_vector_type(8)));
typedef float f32x4 __attribute__((ext_vector_type(4)));

constexpr int D_IN   = 768;
constexpr int D_SAE  = 16384;   // 2^14
constexpr int BATCH  = 4096;
constexpr int TOTAL_K = 64 * 4096;              // 262144
constexpr size_t NPRE = (size_t)BATCH * D_SAE;  // 67,108,864

// ---------------- workspace layout (bytes) ----------------
// ctrl[1]=bA ctrl[2]=C_A ctrl[3]=thr16 ctrl[5]=nCand ctrl[6]=tau ctrl[7]=nt
// ctrl[8]=bB ctrl[9]=C_B ctrl[10]=tiecnt
constexpr size_t CTRL_OFF    = 0;                          // 16 uints
constexpr size_t HISTA_OFF   = 64;                         // 8192 uints (13-bit approx hist)
constexpr size_t HISTB_OFF   = HISTA_OFF + 8192 * 4;       // 4096 uints (top-12 exact)
constexpr size_t HISTC_OFF   = HISTB_OFF + 4096 * 4;       // 4096 uints (mid-12 exact)
constexpr size_t HISTD_OFF   = HISTC_OFF + 4096 * 4;       // 256 uints (low-8 exact)
constexpr size_t ROWCNT_OFF  = HISTD_OFF + 256 * 4;        // BATCH uints
constexpr size_t TIEBUF_OFF  = ROWCNT_OFF + BATCH * 4;     // 2048 uints
constexpr size_t ZERO_BYTES  = TIEBUF_OFF + 2048 * 4;      // memset region end
constexpr size_t ROWOFF_OFF  = ZERO_BYTES;                 // BATCH+1 uints (pad)
constexpr size_t CURSOR_OFF  = ROWOFF_OFF + (BATCH + 64) * 4;
constexpr size_t TIEKEEP_OFF = CURSOR_OFF + BATCH * 4;     // 2048 uints
constexpr int    CAND_CAP    = 1048576;                    // ~2x worst-case band
constexpr size_t CAND_OFF    = TIEKEEP_OFF + 2048 * 4;     // uint2 * CAND_CAP (8 MB)
constexpr size_t GROUPED_OFF = CAND_OFF + (size_t)CAND_CAP * 8;  // uint2*(TOTAL_K+2048)

__device__ __forceinline__ ushort_t f2bf(float f) {        // RNE fp32->bf16 (finite inputs)
  uint u = __float_as_uint(f);
  return (ushort_t)((u + 0x7FFFu + ((u >> 16) & 1u)) >> 16);
}

// ---------------- prep: xc_bf16 = bf16(x - b_dec) ----------------
__global__ __launch_bounds__(256) void prep_x(const float* __restrict__ x,
                                              const float* __restrict__ bdec,
                                              ushort_t* __restrict__ xc)
{
  int i = blockIdx.x * 256 + threadIdx.x;     // one float4 per thread
  int k4 = i % (D_IN / 4), r = i / (D_IN / 4);
  float4 v  = *(const float4*)(x + (size_t)r * D_IN + k4 * 4);
  float4 bd = *(const float4*)(bdec + k4 * 4);
  ushort4 s;
  s.x = f2bf(v.x - bd.x); s.y = f2bf(v.y - bd.y);
  s.z = f2bf(v.z - bd.z); s.w = f2bf(v.w - bd.w);
  *(ushort4*)(xc + (size_t)r * D_IN + k4 * 4) = s;
}

// ---------------- transpose W_enc -> WT_f32 [D_SAE][D_IN] + WT_bf16 ----------------
__global__ __launch_bounds__(256) void transpose_w(const float* __restrict__ W,
                                                   float* __restrict__ wtf,
                                                   ushort_t* __restrict__ wtb)
{
  __shared__ float t[64][65];
  int j0 = blockIdx.x * 64;    // D_SAE block
  int k0 = blockIdx.y * 64;    // D_IN block
  int tx = threadIdx.x & 15, ty = threadIdx.x >> 4;
#pragma unroll
  for (int rr = 0; rr < 4; ++rr) {
    float4 v = *(const float4*)(W + (size_t)(k0 + ty + 16 * rr) * D_SAE + j0 + tx * 4);
    t[tx * 4 + 0][ty + 16 * rr] = v.x;
    t[tx * 4 + 1][ty + 16 * rr] = v.y;
    t[tx * 4 + 2][ty + 16 * rr] = v.z;
    t[tx * 4 + 3][ty + 16 * rr] = v.w;
  }
  __syncthreads();
#pragma unroll
  for (int rr = 0; rr < 4; ++rr) {
    int j = j0 + ty + 16 * rr;
    float4 v;
    v.x = t[ty + 16 * rr][tx * 4 + 0];
    v.y = t[ty + 16 * rr][tx * 4 + 1];
    v.z = t[ty + 16 * rr][tx * 4 + 2];
    v.w = t[ty + 16 * rr][tx * 4 + 3];
    *(float4*)(wtf + (size_t)j * D_IN + k0 + tx * 4) = v;
    ushort4 s;
    s.x = f2bf(v.x); s.y = f2bf(v.y); s.z = f2bf(v.z); s.w = f2bf(v.w);
    *(ushort4*)(wtb + (size_t)j * D_IN + k0 + tx * 4) = s;
  }
}

// ---------------- bf16 MFMA GEMM: pre_b = bf16(relu(xc @ WT^T + b_enc)) ----------------
__global__ __launch_bounds__(256, 3) void mfma_gemm(
    const ushort_t* __restrict__ xc, const ushort_t* __restrict__ wtb,
    const float* __restrict__ benc,
    ushort_t* __restrict__ pre_b, uint* __restrict__ histA)
{
  __shared__ char smem[36864];                 // As 18432 | Bs 18432 ; reused as hist[8192]
  ushort_t* As = (ushort_t*)smem;              // [128][72] (pad 8 -> 144B rows, 16B aligned)
  ushort_t* Bs = (ushort_t*)(smem + 18432);
  const int tid = threadIdx.x;
  const int m0 = blockIdx.y * 128;
  const int n0 = blockIdx.x * 128;
  const int lane = tid & 63;
  const int wave = tid >> 6;
  const int wr = wave >> 1, wc = wave & 1;
  const int l15 = lane & 15, l4 = lane >> 4;
  const int srow = tid >> 1, shalf = tid & 1;  // staging: row, 32-elem half

  f32x4 acc[4][4] = {};

  for (int k0 = 0; k0 < D_IN; k0 += 64) {
    {
      const uint4* sa = (const uint4*)(xc + (size_t)(m0 + srow) * D_IN + k0 + shalf * 32);
      uint4 a0 = sa[0], a1 = sa[1], a2 = sa[2], a3 = sa[3];
      const uint4* sb = (const uint4*)(wtb + (size_t)(n0 + srow) * D_IN + k0 + shalf * 32);
      uint4 b0 = sb[0], b1 = sb[1], b2 = sb[2], b3 = sb[3];
      uint4* da = (uint4*)(As + srow * 72 + shalf * 32);
      da[0] = a0; da[1] = a1; da[2] = a2; da[3] = a3;
      uint4* db = (uint4*)(Bs + srow * 72 + shalf * 32);
      db[0] = b0; db[1] = b1; db[2] = b2; db[3] = b3;
    }
    __syncthreads();
#pragma unroll
    for (int ks = 0; ks < 2; ++ks) {
      bf16x8 a[4], b[4];
#pragma unroll
      for (int m = 0; m < 4; ++m)
        a[m] = *(const bf16x8*)(As + (wr * 64 + m * 16 + l15) * 72 + ks * 32 + l4 * 8);
#pragma unroll
      for (int n = 0; n < 4; ++n)
        b[n] = *(const bf16x8*)(Bs + (wc * 64 + n * 16 + l15) * 72 + ks * 32 + l4 * 8);
#pragma unroll
      for (int m = 0; m < 4; ++m)
#pragma unroll
        for (int n = 0; n < 4; ++n)
          acc[m][n] = __builtin_amdgcn_mfma_f32_16x16x32_bf16(a[m], b[n], acc[m][n], 0, 0, 0);
    }
    __syncthreads();
  }

  // epilogue: +b_enc, relu, bf16 store, 8192-bin LDS hist of bf16 bits>>3
  uint* h = (uint*)smem;
  for (int i = tid; i < 8192; i += 256) h[i] = 0;
  __syncthreads();
#pragma unroll
  for (int m = 0; m < 4; ++m) {
#pragma unroll
    for (int n = 0; n < 4; ++n) {
      int col = n0 + wc * 64 + n * 16 + l15;
      float be = benc[col];
#pragma unroll
      for (int r = 0; r < 4; ++r) {
        int row = m0 + wr * 64 + m * 16 + l4 * 4 + r;
        float v = fmaxf(acc[m][n][r] + be, 0.f);
        ushort_t b16 = f2bf(v);
        pre_b[(size_t)row * D_SAE + col] = b16;
        if (b16) atomicAdd(&h[b16 >> 3], 1u);
      }
    }
  }
  __syncthreads();
  for (int i = tid; i < 8192; i += 256) {
    uint c = h[i];
    if (c) atomicAdd(&histA[i], c);
  }
}

// ---------------- approx-stage: conservative candidate threshold ----------------
__global__ __launch_bounds__(256) void select_thr(const uint* __restrict__ hist, uint* ctrl)
{
  __shared__ uint ssum[256];
  int t = threadIdx.x;
  int hi = 8192 - 32 * t;
  uint sum = 0;
  for (int b = hi - 32; b < hi; ++b) sum += hist[b];
  ssum[t] = sum;
  __syncthreads();
  if (t == 0) {
    uint C = 0;
    int tc = 255;
    for (int i = 0; i < 256; ++i) {
      if (C + ssum[i] >= TOTAL_K) { tc = i; break; }
      C += ssum[i];
    }
    int top = 8192 - 32 * tc - 1;
    uint bin = (uint)(top - 31);
    for (int b = top; b >= top - 31; --b) {
      uint c = hist[b];
      if (C + c >= TOTAL_K) { bin = (uint)b; break; }
      C += c;
    }
    float vlo = __uint_as_float(bin << 19);      // bin lower edge
    float tcf = vlo - 0.0625f;
    uint thr16;
    if (tcf <= 0.f) thr16 = 1u;
    else thr16 = (__float_as_uint(tcf) + 0xFFFFu) >> 16;
    if (thr16 == 0) thr16 = 1u;
    ctrl[3] = thr16;
  }
}

// ---------------- collect candidate indices: approx bits16 >= thr16 ----------------
__global__ __launch_bounds__(256) void collect_cands(const ushort_t* __restrict__ pre_b,
                                                     uint* __restrict__ ctrl, uint2* __restrict__ cand)
{
  __shared__ uint ents[4096];
  __shared__ uint scnt, sbase;
  if (threadIdx.x == 0) scnt = 0;
  __syncthreads();
  uint thr = ctrl[3];
  size_t n8 = NPRE / 8;
  size_t stride = (size_t)gridDim.x * 256;
  for (size_t i = (size_t)blockIdx.x * 256 + threadIdx.x; i < n8; i += stride) {
    uint4 v = ((const uint4*)pre_b)[i];
    uint base = (uint)(i * 8);
    uint vals[8] = {v.x & 0xFFFFu, v.x >> 16, v.y & 0xFFFFu, v.y >> 16,
                    v.z & 0xFFFFu, v.z >> 16, v.w & 0xFFFFu, v.w >> 16};
#pragma unroll
    for (int c = 0; c < 8; ++c) {
      if (vals[c] >= thr) {
        uint p = atomicAdd(&scnt, 1u);
        if (p < 4096) ents[p] = base + c;
        else { uint q = atomicAdd(&ctrl[5], 1u); if (q < CAND_CAP) cand[q] = make_uint2(0u, base + c); }
      }
    }
  }
  __syncthreads();
  uint m = min(scnt, 4096u);
  if (threadIdx.x == 0) sbase = atomicAdd(&ctrl[5], m);
  __syncthreads();
  for (uint i = threadIdx.x; i < m; i += 256) {
    uint p = sbase + i;
    if (p < CAND_CAP) cand[p] = make_uint2(0u, ents[i]);
  }
}

// ---------------- exact recompute: sequential k-ascending fmaf chain ----------------
// Bitwise-identical to the round-1..6 enc_gemm chain.
__global__ __launch_bounds__(256) void recompute(
    const float* __restrict__ x, const float* __restrict__ bdec,
    const float* __restrict__ benc, const float* __restrict__ wtf,
    const uint* __restrict__ ctrl, uint2* __restrict__ cand)
{
  uint nC = min(ctrl[5], (uint)CAND_CAP);
  uint i = blockIdx.x * 256 + threadIdx.x;
  if (i >= nC) return;
  uint idx = cand[i].y;
  uint r = idx >> 14, j = idx & (D_SAE - 1);
  const float* xr = x + (size_t)r * D_IN;
  const float* wr = wtf + (size_t)j * D_IN;
  float a = 0.f;
  for (int k = 0; k < D_IN; k += 4) {
    float4 xv = *(const float4*)(xr + k);
    float4 bd = *(const float4*)(bdec + k);
    float4 wv = *(const float4*)(wr + k);
    a = fmaf(xv.x - bd.x, wv.x, a);
    a = fmaf(xv.y - bd.y, wv.y, a);
    a = fmaf(xv.z - bd.z, wv.z, a);
    a = fmaf(xv.w - bd.w, wv.w, a);
  }
  float v = fmaxf(a + benc[j], 0.f);
  cand[i] = make_uint2(__float_as_uint(v), idx);
}

// ---------------- 12-bit hist of exact bits over candidates ----------------
__global__ __launch_bounds__(256) void hist_exact(const uint* __restrict__ ctrl,
                                                  const uint2* __restrict__ cand,
                                                  uint* __restrict__ histB)
{
  __shared__ uint h[4096];
  for (int i = threadIdx.x; i < 4096; i += 256) h[i] = 0;
  __syncthreads();
  uint nC = min(ctrl[5], (uint)CAND_CAP);
  uint stride = gridDim.x * 256;
  for (uint i = blockIdx.x * 256 + threadIdx.x; i < nC; i += stride)
    atomicAdd(&h[cand[i].x >> 20], 1u);
  __syncthreads();
  for (int i = threadIdx.x; i < 4096; i += 256) {
    uint c = h[i];
    if (c) atomicAdd(&histB[i], c);
  }
}

// ---------------- exact stage-0 crossing-bin search (ctrl[1], ctrl[2]) ----------------
__global__ __launch_bounds__(256) void select_bin(const uint* __restrict__ hist, uint* ctrl)
{
  __shared__ uint ssum[256];
  int t = threadIdx.x;
  int hi = 4096 - 16 * t;
  uint sum = 0;
  for (int b = hi - 16; b < hi; ++b) sum += hist[b];
  ssum[t] = sum;
  __syncthreads();
  if (t == 0) {
    uint C = 0;
    int tc = 255;
    for (int i = 0; i < 256; ++i) {
      if (C + ssum[i] >= TOTAL_K) { tc = i; break; }
      C += ssum[i];
    }
    int top = 4096 - 16 * tc - 1;
    uint bin = (uint)(top - 15);
    for (int b = top; b >= top - 15; --b) {
      uint c = hist[b];
      if (C + c >= TOTAL_K) { bin = (uint)b; break; }
      C += c;
    }
    ctrl[1] = bin;   // bA (exact)
    ctrl[2] = C;     // count strictly above bin bA
  }
}

// ---------------- mid-12-bit hist over candidates inside bin bA (multi-block) ----------------
__global__ __launch_bounds__(256) void hist_mid(const uint* __restrict__ ctrl,
                                                const uint2* __restrict__ cand,
                                                uint* __restrict__ histC)
{
  __shared__ uint h[4096];
  for (int i = threadIdx.x; i < 4096; i += 256) h[i] = 0;
  __syncthreads();
  uint nC = min(ctrl[5], (uint)CAND_CAP);
  uint bA = ctrl[1];
  uint stride = gridDim.x * 256;
  for (uint i = blockIdx.x * 256 + threadIdx.x; i < nC; i += stride) {
    uint b = cand[i].x;
    if ((b >> 20) == bA) atomicAdd(&h[(b >> 8) & 0xFFFu], 1u);
  }
  __syncthreads();
  for (int i = threadIdx.x; i < 4096; i += 256) {
    uint c = h[i];
    if (c) atomicAdd(&histC[i], c);
  }
}

// ---------------- mid crossing-bin search (base C_A -> ctrl[8], ctrl[9]) ----------------
__global__ __launch_bounds__(256) void select_mid(const uint* __restrict__ hist, uint* ctrl)
{
  __shared__ uint ssum[256];
  int t = threadIdx.x;
  int hi = 4096 - 16 * t;
  uint sum = 0;
  for (int b = hi - 16; b < hi; ++b) sum += hist[b];
  ssum[t] = sum;
  __syncthreads();
  if (t == 0) {
    uint C = ctrl[2];
    int tc = 255;
    for (int i = 0; i < 256; ++i) {
      if (C + ssum[i] >= TOTAL_K) { tc = i; break; }
      C += ssum[i];
    }
    int top = 4096 - 16 * tc - 1;
    uint bin = (uint)(top - 15);
    for (int b = top; b >= top - 15; --b) {
      uint c = hist[b];
      if (C + c >= TOTAL_K) { bin = (uint)b; break; }
      C += c;
    }
    ctrl[8] = bin;   // bB
    ctrl[9] = C;     // C_B
  }
}

// ---------------- low-8-bit hist over top24 == target (multi-block) ----------------
__global__ __launch_bounds__(256) void hist_low(const uint* __restrict__ ctrl,
                                                const uint2* __restrict__ cand,
                                                uint* __restrict__ histD)
{
  __shared__ uint h[256];
  h[threadIdx.x] = 0;
  __syncthreads();
  uint nC = min(ctrl[5], (uint)CAND_CAP);
  uint target = (ctrl[1] << 12) | ctrl[8];
  uint stride = gridDim.x * 256;
  for (uint i = blockIdx.x * 256 + threadIdx.x; i < nC; i += stride) {
    uint b = cand[i].x;
    if ((b >> 8) == target) atomicAdd(&h[b & 0xFFu], 1u);
  }
  __syncthreads();
  uint c = h[threadIdx.x];
  if (c) atomicAdd(&histD[threadIdx.x], c);
}

// ---------------- final tau selection (1 tiny block) ----------------
__global__ void select_low(const uint* __restrict__ histD, uint* __restrict__ ctrl)
{
  if (threadIdx.x == 0) {
    uint need = TOTAL_K - ctrl[9];   // >= 1
    uint c = 0, v = 0, cgt = 0;
    for (int b = 255; b >= 0; --b) {
      uint hb = histD[b];
      if (c + hb >= need) { v = (uint)b; cgt = c; break; }
      c += hb;
    }
    uint target = (ctrl[1] << 12) | ctrl[8];
    ctrl[6] = (target << 8) | v;     // tau
    ctrl[7] = need - cgt;            // nt >= 1
  }
}

// ---------------- collect ==tau ties (multi-block) ----------------
__global__ __launch_bounds__(256) void collect_ties(uint* __restrict__ ctrl,
                                                    const uint2* __restrict__ cand,
                                                    uint* __restrict__ tiebuf)
{
  uint nC = min(ctrl[5], (uint)CAND_CAP);
  uint tau = ctrl[6];
  uint stride = gridDim.x * 256;
  for (uint i = blockIdx.x * 256 + threadIdx.x; i < nC; i += stride) {
    if (cand[i].x == tau) {
      uint p = atomicAdd(&ctrl[10], 1u);
      if (p < 2048) tiebuf[p] = cand[i].y;
    }
  }
}

// ---------------- rank ties, keep nt smallest flat indices ----------------
__global__ __launch_bounds__(256) void tie_rank(const uint* __restrict__ ctrl,
                                                const uint* __restrict__ tiebuf,
                                                uint* __restrict__ tiekeep)
{
  __shared__ uint s_tie[2048];
  uint m = min(ctrl[10], 2048u);
  uint nt = ctrl[7];
  for (uint i = threadIdx.x; i < m; i += 256) s_tie[i] = tiebuf[i];
  __syncthreads();
  for (uint i = threadIdx.x; i < m; i += 256) {
    uint my = s_tie[i];
    uint rank = 0;
    for (uint j = 0; j < m; ++j) rank += (s_tie[j] < my) ? 1u : 0u;
    if (rank < nt) tiekeep[rank] = my;
  }
}

// ---------------- scatter kept values into zeroed z + rowcnt ----------------
__global__ __launch_bounds__(256) void scatter_kept(const uint* __restrict__ ctrl, const uint2* __restrict__ cand,
                                                    const uint* __restrict__ tiekeep,
                                                    float* __restrict__ z, uint* __restrict__ rowcnt)
{
  uint nC = min(ctrl[5], (uint)CAND_CAP);
  uint i = blockIdx.x * 256 + threadIdx.x;
  if (i >= nC) return;
  uint tau = ctrl[6], nt = ctrl[7];
  uint2 e = cand[i];
  bool keep = e.x > tau;
  if (!keep && e.x == tau) {
    for (uint j = 0; j < nt; ++j)
      if (tiekeep[j] == e.y) { keep = true; break; }
  }
  if (keep) {
    z[e.y] = __uint_as_float(e.x);
    atomicAdd(&rowcnt[e.y >> 14], 1u);
  }
}

// ---------------- prefix sum over row counts ----------------
__global__ __launch_bounds__(256) void prefix_rows(const uint* __restrict__ rowcnt,
                                                   uint* __restrict__ rowoff, uint* __restrict__ cursor)
{
  __shared__ uint s[256];
  __shared__ uint pref[257];
  int t = threadIdx.x;
  uint loc[16], sum = 0;
#pragma unroll
  for (int r = 0; r < 16; ++r) { loc[r] = rowcnt[t * 16 + r]; sum += loc[r]; }
  s[t] = sum;
  __syncthreads();
  if (t == 0) {
    uint a = 0;
    for (int i = 0; i < 256; ++i) { pref[i] = a; a += s[i]; }
    pref[256] = a;
  }
  __syncthreads();
  uint off = pref[t];
#pragma unroll
  for (int r = 0; r < 16; ++r) {
    rowoff[t * 16 + r] = off;
    cursor[t * 16 + r] = off;
    off += loc[r];
  }
  if (t == 255) rowoff[BATCH] = off;
}

// ---------------- group kept entries by row ----------------
__global__ __launch_bounds__(256) void group_pass(const uint* __restrict__ ctrl, const uint2* __restrict__ cand,
                                                  const uint* __restrict__ tiekeep,
                                                  uint* __restrict__ cursor, uint2* __restrict__ grouped)
{
  uint nC = min(ctrl[5], (uint)CAND_CAP);
  uint i = blockIdx.x * 256 + threadIdx.x;
  if (i >= nC) return;
  uint tau = ctrl[6], nt = ctrl[7];
  uint2 e = cand[i];
  bool keep = e.x > tau;
  if (!keep && e.x == tau) {
    for (uint j = 0; j < nt; ++j)
      if (tiekeep[j] == e.y) { keep = true; break; }
  }
  if (keep) {
    uint p = atomicAdd(&cursor[e.y >> 14], 1u);
    grouped[p] = make_uint2(e.y, e.x);   // (flat idx, bits)
  }
}

// ---------------- sparse decode ----------------
__global__ __launch_bounds__(256) void decode_kernel(const uint* __restrict__ rowoff, const uint2* __restrict__ grouped,
                                                     const float* __restrict__ Wdec, const float* __restrict__ bdec,
                                                     float* __restrict__ xhat)
{
  int r = blockIdx.x;
  int t = threadIdx.x;
  uint beg = rowoff[r], end = rowoff[r + 1];
  float a0 = bdec[t], a1 = bdec[t + 256], a2 = bdec[t + 512];
  __shared__ uint2 ch[128];
  for (uint c0 = beg; c0 < end; c0 += 128) {
    uint m = min(128u, end - c0);
    if (t < (int)m) ch[t] = grouped[c0 + t];
    __syncthreads();
    for (uint e = 0; e < m; ++e) {
      uint2 en = ch[e];
      float v = __uint_as_float(en.y);
      uint j = en.x & (D_SAE - 1);
      const float* wr = Wdec + (size_t)j * D_IN;
      a0 = fmaf(v, wr[t], a0);
      a1 = fmaf(v, wr[t + 256], a1);
      a2 = fmaf(v, wr[t + 512], a2);
    }
    __syncthreads();
  }
  float* out = xhat + (size_t)r * D_IN;
  out[t] = a0; out[t + 256] = a1; out[t + 512] = a2;
}

extern "C" void kernel_launch(void* const* d_in, const int* in_sizes, int n_in,
                              void* d_out, int out_size, void* d_ws, size_t ws_size,
                              hipStream_t stream)
{
  const float* x    = (const float*)d_in[0];
  const float* Wenc = (const float*)d_in[1];
  const float* benc = (const float*)d_in[2];
  const float* Wdec = (const float*)d_in[3];
  const float* bdec = (const float*)d_in[4];

  // d_out: xhat [4096x768 f32] | z [4096x16384 f32]
  // Dead z-region reuse before z is written:
  //   pre_b  (bf16, 134 MB) at z+0
  //   WT_f32 (48 MB)        at z+134MB
  //   WT_bf16(24 MB)        at z+182MB
  // xc_bf16 (6 MB) lives in the xhat region (xhat written last, by decode).
  char* outb = (char*)d_out;
  float*    xhat  = (float*)outb;
  ushort_t* xc    = (ushort_t*)outb;
  char*     zb    = outb + (size_t)BATCH * D_IN * 4;
  float*    z     = (float*)zb;
  ushort_t* pre_b = (ushort_t*)zb;
  float*    wtf   = (float*)(zb + NPRE * 2);
  ushort_t* wtb   = (ushort_t*)(zb + NPRE * 2 + (size_t)D_SAE * D_IN * 4);

  char* ws = (char*)d_ws;
  uint*  ctrl    = (uint*)(ws + CTRL_OFF);
  uint*  histA   = (uint*)(ws + HISTA_OFF);
  uint*  histB   = (uint*)(ws + HISTB_OFF);
  uint*  histC   = (uint*)(ws + HISTC_OFF);
  uint*  histD   = (uint*)(ws + HISTD_OFF);
  uint*  rowcnt  = (uint*)(ws + ROWCNT_OFF);
  uint*  tiebuf  = (uint*)(ws + TIEBUF_OFF);
  uint*  rowoff  = (uint*)(ws + ROWOFF_OFF);
  uint*  cursor  = (uint*)(ws + CURSOR_OFF);
  uint*  tiekeep = (uint*)(ws + TIEKEEP_OFF);
  uint2* cand    = (uint2*)(ws + CAND_OFF);
  uint2* grouped = (uint2*)(ws + GROUPED_OFF);

  (void)hipMemsetAsync(d_ws, 0, ZERO_BYTES, stream);

  prep_x<<<BATCH * D_IN / 4 / 256, 256, 0, stream>>>(x, bdec, xc);
  transpose_w<<<dim3(D_SAE / 64, D_IN / 64), 256, 0, stream>>>(Wenc, wtf, wtb);
  mfma_gemm<<<dim3(D_SAE / 128, BATCH / 128), 256, 0, stream>>>(xc, wtb, benc, pre_b, histA);

  select_thr<<<1, 256, 0, stream>>>(histA, ctrl);
  collect_cands<<<1024, 256, 0, stream>>>(pre_b, ctrl, cand);
  recompute<<<CAND_CAP / 256, 256, 0, stream>>>(x, bdec, benc, wtf, ctrl, cand);

  hist_exact<<<128, 256, 0, stream>>>(ctrl, cand, histB);
  select_bin<<<1, 256, 0, stream>>>(histB, ctrl);
  hist_mid<<<128, 256, 0, stream>>>(ctrl, cand, histC);
  select_mid<<<1, 256, 0, stream>>>(histC, ctrl);
  hist_low<<<128, 256, 0, stream>>>(ctrl, cand, histD);
  select_low<<<1, 64, 0, stream>>>(histD, ctrl);
  collect_ties<<<128, 256, 0, stream>>>(ctrl, cand, tiebuf);
  tie_rank<<<1, 256, 0, stream>>>(ctrl, tiebuf, tiekeep);

  (void)hipMemsetAsync(z, 0, NPRE * 4, stream);
  scatter_kept<<<CAND_CAP / 256, 256, 0, stream>>>(ctrl, cand, tiekeep, z, rowcnt);
  prefix_rows<<<1, 256, 0, stream>>>(rowcnt, rowoff, cursor);
  group_pass<<<CAND_CAP / 256, 256, 0, stream>>>(ctrl, cand, tiekeep, cursor, grouped);
  decode_kernel<<<BATCH, 256, 0, stream>>>(rowoff, grouped, Wdec, bdec, xhat);
}